// Round 8
// baseline (246.141 us; speedup 1.0000x reference)
//
#include <hip/hip_runtime.h>
#include <hip/hip_bf16.h>
#include <math.h>

// Fused QKV(+bias) -> RoPE -> 4-head causal attention -> FC2(+bias) -> SiLU
// B=2048, L=119, D=128, H=4, HD=32. fp32 in/out, bf16 MFMA internally.
// Head split: model channel c = d*4 + h. Head merge: out channel c' = h*32 + d.
//
// Round 7: swapped-operand QK^T keeps P entirely in registers (T12-style).
//  - s[nt] = mfma(K,q): C col = query(ln15), rows = keys (kg*4+r). Softmax is
//    per-lane over in-register keys + 2 shfl_xor; only diagonal tile masked.
//  - P -> bf16 pairs in-register; PV A-fragment built by lane exchange:
//    srcLo = ln15+32*(kg&1), srcHi = srcLo+16, nt = 2kb+(kg>>1) (8 shfl+4 sel
//    per K-block). Normalization deferred to O (shfl'd 1/sum); SCALE folded
//    into q at the QKV epilogue.
//  - Ps LDS buffer GONE: LDS 40,960 -> 24,576 B -> 6 blocks/CU ceiling;
//    the Ps bank conflicts (~4-way b16 writes) gone with it.
// LDS: qs/ks [119][34] (17-word rows, conflict-free), vT [32][128]
// XOR-swizzled ^((row&7)<<3) both sides (rule #21).
// MFMA 16x16x32_bf16: A/B lane&15=row/col, k=(lane>>4)*8+j; C/D col=lane&15,
// row=(lane>>4)*4+reg [m89].

#define L_SEQ 119
#define D_MODEL 128
#define SCALE 0.17677669529663687f  // 1/sqrt(32)
#define NEGINF -1e30f

typedef __bf16 bf16x8 __attribute__((ext_vector_type(8)));
typedef __bf16 bf16x2 __attribute__((ext_vector_type(2)));
typedef float f32x4 __attribute__((ext_vector_type(4)));

__global__ void rope_tab_kernel(float2* __restrict__ tab) {
  int i = blockIdx.x * blockDim.x + threadIdx.x;
  if (i >= L_SEQ * 64) return;
  int l = i >> 6, j = i & 63;
  float inv = 1.0f / powf(10000.0f, (float)(2 * j) / 128.0f);
  float f = (float)l * inv;
  float c = cosf(f), s = sinf(f);
  tab[i] = make_float2(__bfloat162float(__float2bfloat16(c)),
                       __bfloat162float(__float2bfloat16(s)));
}

// Wb fragment layout: flat = ((nt*4 + kb)*64 + lane)*8 + j
//   reordered channel n~ = nt*16 + (lane&15); k = kb*32 + (lane>>4)*8 + j
//   n~ = h*96 + qkv*32 + d  ->  source row = qkv*128 + d*4 + h
__global__ void wprep_kernel(const float* __restrict__ Wqkv,
                             const float* __restrict__ bqkv,
                             __bf16* __restrict__ Wb, float* __restrict__ bb) {
  int i = blockIdx.x * 256 + threadIdx.x;  // 0..49151
  int j = i & 7, lane = (i >> 3) & 63, kb = (i >> 9) & 3, nt = i >> 11;
  int ln15 = lane & 15;
  int nch = nt * 16 + ln15;
  int h = nch / 96, rem = nch % 96, qkv = rem >> 5, d = rem & 31;
  int srow = qkv * 128 + d * 4 + h;
  int k = kb * 32 + (lane >> 4) * 8 + j;
  Wb[i] = (__bf16)Wqkv[srow * 128 + k];
  if (i < 384) {
    int h2 = i / 96, r2 = i % 96, q2 = r2 >> 5, d2 = r2 & 31;
    bb[i] = bqkv[q2 * 128 + d2 * 4 + h2];
  }
}

__global__ __launch_bounds__(256) void fused_qkv_attn(
    const float* __restrict__ x, const __bf16* __restrict__ Wb,
    const float* __restrict__ bb, const float2* __restrict__ tab,
    float* __restrict__ out) {
  __shared__ __align__(16) __bf16 qs[119 * 34];  //  8,092 B
  __shared__ __align__(16) __bf16 ks[119 * 34];  //  8,092 B
  __shared__ __align__(16) __bf16 vT[32 * 128];  //  8,192 B (XOR-swizzled)

  const int t = threadIdx.x;
  const int b = blockIdx.x >> 2, h = blockIdx.x & 3;
  const int lane = t & 63, wv = t >> 6;  // wv in 0..3
  const int ln15 = lane & 15, kg = lane >> 4;
  const int msel = wv;  // wave's M-tiles: {msel, msel+4}

  // ---- zero vT tail cols 119..127 (PV kb=3 touches them; P=0 there but
  // stale LDS could be NaN and NaN*0=NaN in MFMA)
  for (int i = t; i < 32 * 9; i += 256) {
    int rr = i / 9, cc = L_SEQ + i % 9;
    vT[rr * 128 + (cc ^ ((rr & 7) << 3))] = (__bf16)0.0f;
  }

  // ---- x A-fragments for the wave's two M-tiles
  bf16x8 af[2][4];
#pragma unroll
  for (int ms = 0; ms < 2; ++ms) {
    int xr = (msel + ms * 4) * 16 + ln15;
    if (xr > L_SEQ - 1) xr = L_SEQ - 1;
    const float* xrow = x + ((size_t)b * L_SEQ + xr) * 128;
#pragma unroll
    for (int kb = 0; kb < 4; ++kb) {
      float4 lo = *(const float4*)&xrow[kb * 32 + kg * 8];
      float4 hi = *(const float4*)&xrow[kb * 32 + kg * 8 + 4];
      bf16x8 v;
      v[0] = (__bf16)lo.x; v[1] = (__bf16)lo.y; v[2] = (__bf16)lo.z; v[3] = (__bf16)lo.w;
      v[4] = (__bf16)hi.x; v[5] = (__bf16)hi.y; v[6] = (__bf16)hi.z; v[7] = (__bf16)hi.w;
      af[ms][kb] = v;
    }
  }

  // ---- QKV in 3 channel-pairs (q, k, v), epilogue after each pair
#pragma unroll
  for (int pair = 0; pair < 3; ++pair) {
    f32x4 acc[2][2] = {};  // [ms][half]
#pragma unroll
    for (int half = 0; half < 2; ++half) {
      const int nt = h * 6 + pair * 2 + half;
      bf16x8 wf[4];
#pragma unroll
      for (int kb = 0; kb < 4; ++kb)
        wf[kb] = *(const bf16x8*)&Wb[(((nt * 4 + kb) * 64) + lane) * 8];
#pragma unroll
      for (int kb = 0; kb < 4; ++kb) {
        acc[0][half] = __builtin_amdgcn_mfma_f32_16x16x32_bf16(af[0][kb], wf[kb], acc[0][half], 0, 0, 0);
        acc[1][half] = __builtin_amdgcn_mfma_f32_16x16x32_bf16(af[1][kb], wf[kb], acc[1][half], 0, 0, 0);
      }
    }
    const float b0 = bb[(h * 6 + pair * 2) * 16 + ln15];
    const float b1 = bb[(h * 6 + pair * 2 + 1) * 16 + ln15];
#pragma unroll
    for (int ms = 0; ms < 2; ++ms) {
      const int mt = msel + ms * 4;
#pragma unroll
      for (int r = 0; r < 4; ++r) {
        int l = mt * 16 + kg * 4 + r;
        if (l < L_SEQ) {
          float v1 = acc[ms][0][r] + b0, v2 = acc[ms][1][r] + b1;
          if (pair < 2) {
            // RoPE + packed store, cols (2d,2d+1) <- (y1_d, y2_d); same
            // interleave on q and k => QK^T invariant. SCALE folded into q.
            float2 cs = tab[l * 64 + 4 * ln15 + h];
            if (pair == 0) { v1 *= SCALE; v2 *= SCALE; }
            bf16x2 pk;
            pk[0] = (__bf16)(v1 * cs.x + v2 * cs.y);
            pk[1] = (__bf16)(v2 * cs.x - v1 * cs.y);
            __bf16* base = pair ? ks : qs;
            *(bf16x2*)&base[l * 34 + 2 * ln15] = pk;
          } else {
            int vr0 = ln15, vr1 = ln15 + 16;
            vT[vr0 * 128 + (l ^ ((vr0 & 7) << 3))] = (__bf16)v1;
            vT[vr1 * 128 + (l ^ ((vr1 & 7) << 3))] = (__bf16)v2;
          }
        }
      }
    }
  }
  __syncthreads();  // the ONLY barrier (4 waves)

  // ---- attention, swapped orientation: query = ln15 (per-lane), keys in regs
  const int srcLo = ln15 + ((kg & 1) << 5);
  const int srcHi = srcLo + 16;
#pragma unroll
  for (int ms = 0; ms < 2; ++ms) {
    const int m2 = msel + ms * 4;  // wave-uniform
    int qrow = m2 * 16 + ln15;
    if (qrow > L_SEQ - 1) qrow = L_SEQ - 1;
    bf16x8 qf = *(const bf16x8*)&qs[qrow * 34 + kg * 8];
    // S^T tiles: s[nt] = K_tile[nt] x q_tile  (A=K: rows=keys; B=q: cols=queries)
    f32x4 s[8];
#pragma unroll
    for (int nt = 0; nt < 8; ++nt) {
      if (nt <= m2) {
        int krow = nt * 16 + ln15;
        if (krow > L_SEQ - 1) krow = L_SEQ - 1;
        bf16x8 kf = *(const bf16x8*)&ks[krow * 34 + kg * 8];
        f32x4 z = {};
        s[nt] = __builtin_amdgcn_mfma_f32_16x16x32_bf16(kf, qf, z, 0, 0, 0);
      }
    }
    // causal mask: only diagonal tile needs it (key kg*4+r <= query ln15)
    float mx = NEGINF;
#pragma unroll
    for (int nt = 0; nt < 8; ++nt) {
      if (nt <= m2) {
        if (nt == m2) {
#pragma unroll
          for (int r = 0; r < 4; ++r)
            s[nt][r] = (kg * 4 + r <= ln15) ? s[nt][r] : NEGINF;
        }
#pragma unroll
        for (int r = 0; r < 4; ++r) mx = fmaxf(mx, s[nt][r]);
      }
    }
    mx = fmaxf(mx, __shfl_xor(mx, 16));
    mx = fmaxf(mx, __shfl_xor(mx, 32));
    float sum = 0.0f;
#pragma unroll
    for (int nt = 0; nt < 8; ++nt) {
      if (nt <= m2) {
#pragma unroll
        for (int r = 0; r < 4; ++r) { s[nt][r] = __expf(s[nt][r] - mx); sum += s[nt][r]; }
      }
    }
    sum += __shfl_xor(sum, 16);
    sum += __shfl_xor(sum, 32);
    float inv = 1.0f / sum;  // normalization deferred to O epilogue
    // pack unnormalized P to bf16 pairs (keys r,r+1 adjacent in-lane)
    unsigned pk01[8], pk23[8];
#pragma unroll
    for (int nt = 0; nt < 8; ++nt) { pk01[nt] = 0u; pk23[nt] = 0u; }
#pragma unroll
    for (int nt = 0; nt < 8; ++nt) {
      if (nt <= m2) {
        union { bf16x2 v; unsigned u; } a, bcc;
        a.v[0] = (__bf16)s[nt][0]; a.v[1] = (__bf16)s[nt][1];
        bcc.v[0] = (__bf16)s[nt][2]; bcc.v[1] = (__bf16)s[nt][3];
        pk01[nt] = a.u; pk23[nt] = bcc.u;
      }
    }
    // PV: A-frag(lane q=ln15, keys kb*32+kg*8+j) via lane exchange
    f32x4 o[2] = {};
#pragma unroll
    for (int kb = 0; kb < 4; ++kb) {
      if (kb <= (m2 >> 1)) {  // wave-uniform causal skip
        unsigned e0 = (unsigned)__shfl((int)pk01[2 * kb], srcLo);
        unsigned o0 = (unsigned)__shfl((int)pk01[2 * kb + 1], srcLo);
        unsigned e1 = (unsigned)__shfl((int)pk23[2 * kb], srcLo);
        unsigned o1 = (unsigned)__shfl((int)pk23[2 * kb + 1], srcLo);
        unsigned e2 = (unsigned)__shfl((int)pk01[2 * kb], srcHi);
        unsigned o2 = (unsigned)__shfl((int)pk01[2 * kb + 1], srcHi);
        unsigned e3 = (unsigned)__shfl((int)pk23[2 * kb], srcHi);
        unsigned o3 = (unsigned)__shfl((int)pk23[2 * kb + 1], srcHi);
        const bool odd = (kg & 2) != 0;  // nt = 2kb + (kg>>1)
        union { unsigned w[4]; bf16x8 v; } A;
        A.w[0] = odd ? o0 : e0;
        A.w[1] = odd ? o1 : e1;
        A.w[2] = odd ? o2 : e2;
        A.w[3] = odd ? o3 : e3;
#pragma unroll
        for (int n2 = 0; n2 < 2; ++n2) {
          int vr = n2 * 16 + ln15;
          bf16x8 vf = *(const bf16x8*)&vT[vr * 128 + ((kb * 32 + kg * 8) ^ ((vr & 7) << 3))];
          o[n2] = __builtin_amdgcn_mfma_f32_16x16x32_bf16(A.v, vf, o[n2], 0, 0, 0);
        }
      }
    }
    // O rows = queries kg*4+r: fetch that query's 1/sum from lane kg*4+r
    float invr[4];
#pragma unroll
    for (int r = 0; r < 4; ++r) invr[r] = __shfl(inv, kg * 4 + r);
#pragma unroll
    for (int n2 = 0; n2 < 2; ++n2)
#pragma unroll
      for (int r = 0; r < 4; ++r) {
        int l = m2 * 16 + kg * 4 + r;
        if (l < L_SEQ)
          out[((size_t)b * L_SEQ + l) * 128 + h * 32 + n2 * 16 + ln15] =
              o[n2][r] * invr[r];
      }
  }
}

// FC2 + bias + SiLU via MFMA, in-place on d_out. Block owns 128 rows.
__global__ __launch_bounds__(256) void fc2_silu_kernel(
    const float* __restrict__ Wfc2, const float* __restrict__ bfc2,
    float* __restrict__ io) {
  __shared__ __align__(16) __bf16 yl[128 * 136];
  __shared__ __align__(16) __bf16 wl[128 * 136];
  __shared__ float blc[128];
  const int t = threadIdx.x;
  const size_t r0 = (size_t)blockIdx.x * 128;
  for (int i = t; i < 128 * 32; i += 256) {
    int row = i >> 5, c4 = i & 31;
    float4 a = *(const float4*)&io[(r0 + row) * 128 + c4 * 4];
    float4 w = *(const float4*)&Wfc2[row * 128 + c4 * 4];
    __bf16* yd = &yl[row * 136 + c4 * 4];
    yd[0] = (__bf16)a.x; yd[1] = (__bf16)a.y; yd[2] = (__bf16)a.z; yd[3] = (__bf16)a.w;
    __bf16* wd = &wl[row * 136 + c4 * 4];
    wd[0] = (__bf16)w.x; wd[1] = (__bf16)w.y; wd[2] = (__bf16)w.z; wd[3] = (__bf16)w.w;
  }
  if (t < 128) blc[t] = bfc2[t];
  __syncthreads();
  const int lane = t & 63, wv = t >> 6;
  const int ln15 = lane & 15, kg = lane >> 4;
#pragma unroll
  for (int mm = 0; mm < 2; ++mm) {
    int mtl = wv * 2 + mm;
    bf16x8 af[4];
#pragma unroll
    for (int kb = 0; kb < 4; ++kb)
      af[kb] = *(const bf16x8*)&yl[(mtl * 16 + ln15) * 136 + kb * 32 + kg * 8];
#pragma unroll
    for (int nt = 0; nt < 8; ++nt) {
      f32x4 acc = {};
#pragma unroll
      for (int kb = 0; kb < 4; ++kb)
        acc = __builtin_amdgcn_mfma_f32_16x16x32_bf16(
            af[kb], *(const bf16x8*)&wl[(nt * 16 + ln15) * 136 + kb * 32 + kg * 8],
            acc, 0, 0, 0);
#pragma unroll
      for (int r = 0; r < 4; ++r) {
        int row = mtl * 16 + kg * 4 + r, c = nt * 16 + ln15;
        float vv = acc[r] + blc[c];
        io[(r0 + row) * 128 + c] = vv / (1.0f + __expf(-vv));
      }
    }
  }
}

extern "C" void kernel_launch(void* const* d_in, const int* in_sizes, int n_in,
                              void* d_out, int out_size, void* d_ws,
                              size_t ws_size, hipStream_t stream) {
  const float* x = (const float*)d_in[0];
  const float* Wqkv = (const float*)d_in[1];
  const float* bqkv = (const float*)d_in[2];
  const float* Wfc2 = (const float*)d_in[3];
  const float* bfc2 = (const float*)d_in[4];
  float* out = (float*)d_out;

  char* ws = (char*)d_ws;
  float2* tab = (float2*)ws;                  // 60,928 B
  __bf16* Wb = (__bf16*)(ws + 61440);         // 98,304 B
  float* bb = (float*)(ws + 61440 + 98304);   // 1,536 B  (total 161,280 B)

  const int B = in_sizes[0] / (L_SEQ * D_MODEL);  // 2048
  rope_tab_kernel<<<(L_SEQ * 64 + 255) / 256, 256, 0, stream>>>(tab);
  wprep_kernel<<<192, 256, 0, stream>>>(Wqkv, bqkv, Wb, bb);
  fused_qkv_attn<<<B * 4, 256, 0, stream>>>(x, Wb, bb, tab, out);
  fc2_silu_kernel<<<(B * L_SEQ) / 128, 256, 0, stream>>>(Wfc2, bfc2, out);
}

// Round 9
// 231.278 us; speedup vs baseline: 1.0643x; 1.0643x over previous
//
#include <hip/hip_runtime.h>
#include <hip/hip_bf16.h>
#include <math.h>

// Fused QKV(+bias) -> RoPE -> 4-head causal attention -> FC2(+bias) -> SiLU
// B=2048, L=119, D=128, H=4, HD=32. fp32 in/out, bf16 MFMA internally.
// Head split: model channel c = d*4 + h. Head merge: out channel c' = h*32 + d.
//
// Round 8: MEGA-FUSION — fc2 kernel deleted; its work moves into the per-batch
// kernel after attention (saves a full 250 MB HBM round-trip + a launch).
//   Block = batch b, 512 thr / 8 waves.
//   g=0,1 head-group phases (R5 QKV structure) -> attention (R7 in-register-P,
//   balanced tasks m2 in {ww, 7-ww}) -> y to out (fp32) -> final barrier
//   (vmcnt drained before s_barrier => block-local L2 visibility) -> FC2 phase:
//   wave w reads its 16 y-rows from out (L2-hot), MFMA vs pre-fragmented
//   bf16 Wfc2, bias+SiLU, in-place write (wave-disjoint rows; every element
//   rewritten every call => graph-replay safe).
// LDS: qs/ks [2][119][34] + vT [2][32][128] = 48,752 B (no exact-fit trap).
// RoPE table stored bf16x2 (reference rounds tables to bf16 => identical).
// MFMA 16x16x32_bf16: A/B lane&15=row/col, k=(lane>>4)*8+j; C/D col=lane&15,
// row=(lane>>4)*4+reg [m89].

#define L_SEQ 119
#define D_MODEL 128
#define SCALE 0.17677669529663687f  // 1/sqrt(32)
#define NEGINF -1e30f

typedef __bf16 bf16x8 __attribute__((ext_vector_type(8)));
typedef __bf16 bf16x2 __attribute__((ext_vector_type(2)));
typedef float f32x4 __attribute__((ext_vector_type(4)));

__global__ void rope_tab_kernel(bf16x2* __restrict__ tabb) {
  int i = blockIdx.x * blockDim.x + threadIdx.x;
  if (i >= L_SEQ * 64) return;
  int l = i >> 6, j = i & 63;
  float inv = 1.0f / powf(10000.0f, (float)(2 * j) / 128.0f);
  float f = (float)l * inv;
  bf16x2 cs;
  cs[0] = (__bf16)cosf(f);
  cs[1] = (__bf16)sinf(f);
  tabb[i] = cs;
}

// Wb fragment layout: flat = ((nt*4 + kb)*64 + lane)*8 + j
//   reordered channel n~ = nt*16 + (lane&15); k = kb*32 + (lane>>4)*8 + j
//   n~ = h*96 + qkv*32 + d  ->  source row = qkv*128 + d*4 + h
__global__ void wprep_kernel(const float* __restrict__ Wqkv,
                             const float* __restrict__ bqkv,
                             __bf16* __restrict__ Wb, float* __restrict__ bb) {
  int i = blockIdx.x * 256 + threadIdx.x;  // 0..49151
  int j = i & 7, lane = (i >> 3) & 63, kb = (i >> 9) & 3, nt = i >> 11;
  int ln15 = lane & 15;
  int nch = nt * 16 + ln15;
  int h = nch / 96, rem = nch % 96, qkv = rem >> 5, d = rem & 31;
  int srow = qkv * 128 + d * 4 + h;
  int k = kb * 32 + (lane >> 4) * 8 + j;
  Wb[i] = (__bf16)Wqkv[srow * 128 + k];
  if (i < 384) {
    int h2 = i / 96, r2 = i % 96, q2 = r2 >> 5, d2 = r2 & 31;
    bb[i] = bqkv[q2 * 128 + d2 * 4 + h2];
  }
}

// Wfc2 fragment prep: flat = ((nt*4 + kb)*64 + lane)*8 + j, nt<8
//   n = nt*16 + (lane&15) (output channel), k = kb*32 + (lane>>4)*8 + j
__global__ void wprep2_kernel(const float* __restrict__ Wfc2,
                              __bf16* __restrict__ Wf2b) {
  int i = blockIdx.x * 256 + threadIdx.x;  // 0..16383
  int j = i & 7, lane = (i >> 3) & 63, kb = (i >> 9) & 3, nt = i >> 11;
  int n = nt * 16 + (lane & 15);
  int k = kb * 32 + (lane >> 4) * 8 + j;
  Wf2b[i] = (__bf16)Wfc2[n * 128 + k];
}

__global__ __launch_bounds__(512) void fused_all(
    const float* __restrict__ x, const __bf16* __restrict__ Wb,
    const float* __restrict__ bb, const bf16x2* __restrict__ tabb,
    const __bf16* __restrict__ Wf2b, const float* __restrict__ bfc2,
    float* __restrict__ out) {
  __shared__ __align__(16) __bf16 qs[2 * 119 * 34];  // 16,184 B
  __shared__ __align__(16) __bf16 ks[2 * 119 * 34];  // 16,184 B
  __shared__ __align__(16) __bf16 vT[2 * 32 * 128];  // 16,384 B (XOR-swizzled)

  const int t = threadIdx.x, b = blockIdx.x;
  const int lane = t & 63, wv = t >> 6;
  const int ln15 = lane & 15, kg = lane >> 4;
  const int ww = wv & 3, hh = wv >> 2;  // QKV: M-tiles {ww, ww+4}, local head hh

  // ---- zero vT tail cols 119..127 once (never overwritten: epilogue guards l<119)
  for (int i = t; i < 2 * 32 * 9; i += 512) {
    int hl = i / 288, rem = i % 288, rr = rem / 9, cc = L_SEQ + rem % 9;
    int vr = hl * 32 + rr;
    vT[vr * 128 + (cc ^ ((vr & 7) << 3))] = (__bf16)0.0f;
  }

  for (int g = 0; g < 2; ++g) {
    if (g) __syncthreads();  // prior group's attention done with LDS

    // ---- x A-fragments (per group; L2-hot for g=1)
    bf16x8 af[2][4];
#pragma unroll
    for (int ms = 0; ms < 2; ++ms) {
      int xr = (ww + ms * 4) * 16 + ln15;
      if (xr > L_SEQ - 1) xr = L_SEQ - 1;
      const float* xrow = x + ((size_t)b * L_SEQ + xr) * 128;
#pragma unroll
      for (int kb = 0; kb < 4; ++kb) {
        float4 lo = *(const float4*)&xrow[kb * 32 + kg * 8];
        float4 hi = *(const float4*)&xrow[kb * 32 + kg * 8 + 4];
        bf16x8 v;
        v[0] = (__bf16)lo.x; v[1] = (__bf16)lo.y; v[2] = (__bf16)lo.z; v[3] = (__bf16)lo.w;
        v[4] = (__bf16)hi.x; v[5] = (__bf16)hi.y; v[6] = (__bf16)hi.z; v[7] = (__bf16)hi.w;
        af[ms][kb] = v;
      }
    }

    const int h = 2 * g + hh;
    // ---- QKV in 3 channel-pairs (q, k, v) for head h, 2 M-tiles
#pragma unroll
    for (int pair = 0; pair < 3; ++pair) {
      f32x4 acc[2][2] = {};  // [ms][half]
#pragma unroll
      for (int half = 0; half < 2; ++half) {
        const int nt = g * 12 + hh * 6 + pair * 2 + half;
        bf16x8 wf[4];
#pragma unroll
        for (int kb = 0; kb < 4; ++kb)
          wf[kb] = *(const bf16x8*)&Wb[(((nt * 4 + kb) * 64) + lane) * 8];
#pragma unroll
        for (int kb = 0; kb < 4; ++kb) {
          acc[0][half] = __builtin_amdgcn_mfma_f32_16x16x32_bf16(af[0][kb], wf[kb], acc[0][half], 0, 0, 0);
          acc[1][half] = __builtin_amdgcn_mfma_f32_16x16x32_bf16(af[1][kb], wf[kb], acc[1][half], 0, 0, 0);
        }
      }
      const float b0 = bb[(g * 12 + hh * 6 + pair * 2) * 16 + ln15];
      const float b1 = bb[(g * 12 + hh * 6 + pair * 2 + 1) * 16 + ln15];
#pragma unroll
      for (int ms = 0; ms < 2; ++ms) {
        const int mt = ww + ms * 4;
#pragma unroll
        for (int r = 0; r < 4; ++r) {
          int l = mt * 16 + kg * 4 + r;
          if (l < L_SEQ) {
            float v1 = acc[ms][0][r] + b0, v2 = acc[ms][1][r] + b1;
            if (pair < 2) {
              // RoPE + packed store, cols (2d,2d+1) <- (y1,y2); same interleave
              // on q and k => QK^T invariant. SCALE folded into q.
              bf16x2 tcs = tabb[l * 64 + 4 * ln15 + h];
              float cs0 = (float)tcs[0], cs1 = (float)tcs[1];
              if (pair == 0) { v1 *= SCALE; v2 *= SCALE; }
              bf16x2 pk;
              pk[0] = (__bf16)(v1 * cs0 + v2 * cs1);
              pk[1] = (__bf16)(v2 * cs0 - v1 * cs1);
              __bf16* base = pair ? ks : qs;
              *(bf16x2*)&base[(hh * L_SEQ + l) * 34 + 2 * ln15] = pk;
            } else {
              int vr0 = hh * 32 + ln15, vr1 = vr0 + 16;
              vT[vr0 * 128 + (l ^ ((vr0 & 7) << 3))] = (__bf16)v1;
              vT[vr1 * 128 + (l ^ ((vr1 & 7) << 3))] = (__bf16)v2;
            }
          }
        }
      }
    }
    __syncthreads();

    // ---- attention (swapped orientation, P in registers). 2 balanced tasks:
    // m2 = ww and 7-ww  (QK^T tiles per wave = (ww+1)+(8-ww) = 9, constant)
    const int srcLo = ln15 + ((kg & 1) << 5);
    const int srcHi = srcLo + 16;
#pragma unroll
    for (int ms = 0; ms < 2; ++ms) {
      const int m2 = ms ? (7 - ww) : ww;  // wave-uniform
      int qrow = m2 * 16 + ln15;
      if (qrow > L_SEQ - 1) qrow = L_SEQ - 1;
      bf16x8 qf = *(const bf16x8*)&qs[(hh * L_SEQ + qrow) * 34 + kg * 8];
      f32x4 s[8];
#pragma unroll
      for (int nt = 0; nt < 8; ++nt) {
        if (nt <= m2) {
          int krow = nt * 16 + ln15;
          if (krow > L_SEQ - 1) krow = L_SEQ - 1;
          bf16x8 kf = *(const bf16x8*)&ks[(hh * L_SEQ + krow) * 34 + kg * 8];
          f32x4 z = {};
          s[nt] = __builtin_amdgcn_mfma_f32_16x16x32_bf16(kf, qf, z, 0, 0, 0);
        }
      }
      float mx = NEGINF;
#pragma unroll
      for (int nt = 0; nt < 8; ++nt) {
        if (nt <= m2) {
          if (nt == m2) {
#pragma unroll
            for (int r = 0; r < 4; ++r)
              s[nt][r] = (kg * 4 + r <= ln15) ? s[nt][r] : NEGINF;
          }
#pragma unroll
          for (int r = 0; r < 4; ++r) mx = fmaxf(mx, s[nt][r]);
        }
      }
      mx = fmaxf(mx, __shfl_xor(mx, 16));
      mx = fmaxf(mx, __shfl_xor(mx, 32));
      float sum = 0.0f;
#pragma unroll
      for (int nt = 0; nt < 8; ++nt) {
        if (nt <= m2) {
#pragma unroll
          for (int r = 0; r < 4; ++r) { s[nt][r] = __expf(s[nt][r] - mx); sum += s[nt][r]; }
        }
      }
      sum += __shfl_xor(sum, 16);
      sum += __shfl_xor(sum, 32);
      float inv = 1.0f / sum;  // normalization deferred to O epilogue
      unsigned pk01[8], pk23[8];
#pragma unroll
      for (int nt = 0; nt < 8; ++nt) { pk01[nt] = 0u; pk23[nt] = 0u; }
#pragma unroll
      for (int nt = 0; nt < 8; ++nt) {
        if (nt <= m2) {
          union { bf16x2 v; unsigned u; } a, bcc;
          a.v[0] = (__bf16)s[nt][0]; a.v[1] = (__bf16)s[nt][1];
          bcc.v[0] = (__bf16)s[nt][2]; bcc.v[1] = (__bf16)s[nt][3];
          pk01[nt] = a.u; pk23[nt] = bcc.u;
        }
      }
      f32x4 o[2] = {};
#pragma unroll
      for (int kb = 0; kb < 4; ++kb) {
        if (kb <= (m2 >> 1)) {
          unsigned e0 = (unsigned)__shfl((int)pk01[2 * kb], srcLo);
          unsigned o0 = (unsigned)__shfl((int)pk01[2 * kb + 1], srcLo);
          unsigned e1 = (unsigned)__shfl((int)pk23[2 * kb], srcLo);
          unsigned o1 = (unsigned)__shfl((int)pk23[2 * kb + 1], srcLo);
          unsigned e2 = (unsigned)__shfl((int)pk01[2 * kb], srcHi);
          unsigned o2 = (unsigned)__shfl((int)pk01[2 * kb + 1], srcHi);
          unsigned e3 = (unsigned)__shfl((int)pk23[2 * kb], srcHi);
          unsigned o3 = (unsigned)__shfl((int)pk23[2 * kb + 1], srcHi);
          const bool odd = (kg & 2) != 0;  // nt = 2kb + (kg>>1)
          union { unsigned w[4]; bf16x8 v; } A;
          A.w[0] = odd ? o0 : e0;
          A.w[1] = odd ? o1 : e1;
          A.w[2] = odd ? o2 : e2;
          A.w[3] = odd ? o3 : e3;
#pragma unroll
          for (int n2 = 0; n2 < 2; ++n2) {
            int vr = hh * 32 + n2 * 16 + ln15;
            bf16x8 vf = *(const bf16x8*)&vT[vr * 128 + ((kb * 32 + kg * 8) ^ ((vr & 7) << 3))];
            o[n2] = __builtin_amdgcn_mfma_f32_16x16x32_bf16(A.v, vf, o[n2], 0, 0, 0);
          }
        }
      }
      float invr[4];
#pragma unroll
      for (int r = 0; r < 4; ++r) invr[r] = __shfl(inv, kg * 4 + r);
#pragma unroll
      for (int n2 = 0; n2 < 2; ++n2)
#pragma unroll
        for (int r = 0; r < 4; ++r) {
          int l = m2 * 16 + kg * 4 + r;
          if (l < L_SEQ)
            out[((size_t)b * L_SEQ + l) * 128 + h * 32 + n2 * 16 + ln15] =
                o[n2][r] * invr[r];
        }
    }
  }

  // ---- FC2 + bias + SiLU phase. Barrier drains vmcnt(0) before s_barrier =>
  // all y-writes above are L2-visible to this block. Wave w owns M-tile w
  // (rows w*16..w*16+15): reads its own y rows (L2-hot), in-place rewrite.
  __syncthreads();
  {
    int yr = wv * 16 + ln15;
    if (yr > L_SEQ - 1) yr = L_SEQ - 1;
    const float* yrow = out + ((size_t)b * L_SEQ + yr) * 128;
    bf16x8 af2[4];
#pragma unroll
    for (int kb = 0; kb < 4; ++kb) {
      float4 lo = *(const float4*)&yrow[kb * 32 + kg * 8];
      float4 hi = *(const float4*)&yrow[kb * 32 + kg * 8 + 4];
      bf16x8 v;
      v[0] = (__bf16)lo.x; v[1] = (__bf16)lo.y; v[2] = (__bf16)lo.z; v[3] = (__bf16)lo.w;
      v[4] = (__bf16)hi.x; v[5] = (__bf16)hi.y; v[6] = (__bf16)hi.z; v[7] = (__bf16)hi.w;
      af2[kb] = v;
    }
    float bc[8];
#pragma unroll
    for (int nt = 0; nt < 8; ++nt) bc[nt] = bfc2[nt * 16 + ln15];
    f32x4 acc2[8] = {};
#pragma unroll
    for (int nt = 0; nt < 8; ++nt)
#pragma unroll
      for (int kb = 0; kb < 4; ++kb)
        acc2[nt] = __builtin_amdgcn_mfma_f32_16x16x32_bf16(
            af2[kb], *(const bf16x8*)&Wf2b[(((nt * 4 + kb) * 64) + lane) * 8],
            acc2[nt], 0, 0, 0);
#pragma unroll
    for (int nt = 0; nt < 8; ++nt)
#pragma unroll
      for (int r = 0; r < 4; ++r) {
        int row = wv * 16 + kg * 4 + r, c = nt * 16 + ln15;
        if (row < L_SEQ) {
          float vv = acc2[nt][r] + bc[nt];
          out[((size_t)b * L_SEQ + row) * 128 + c] = vv / (1.0f + __expf(-vv));
        }
      }
  }
}

extern "C" void kernel_launch(void* const* d_in, const int* in_sizes, int n_in,
                              void* d_out, int out_size, void* d_ws,
                              size_t ws_size, hipStream_t stream) {
  const float* x = (const float*)d_in[0];
  const float* Wqkv = (const float*)d_in[1];
  const float* bqkv = (const float*)d_in[2];
  const float* Wfc2 = (const float*)d_in[3];
  const float* bfc2 = (const float*)d_in[4];
  float* out = (float*)d_out;

  char* ws = (char*)d_ws;
  bf16x2* tabb = (bf16x2*)ws;                    // 30,464 B (pad to 30,720)
  __bf16* Wb = (__bf16*)(ws + 30720);            // 98,304 B
  float* bb = (float*)(ws + 30720 + 98304);      //  1,536 B
  __bf16* Wf2b = (__bf16*)(ws + 30720 + 98304 + 1536);  // 32,768 B (end 163,328)

  const int B = in_sizes[0] / (L_SEQ * D_MODEL);  // 2048
  rope_tab_kernel<<<(L_SEQ * 64 + 255) / 256, 256, 0, stream>>>(tabb);
  wprep_kernel<<<192, 256, 0, stream>>>(Wqkv, bqkv, Wb, bb);
  wprep2_kernel<<<64, 256, 0, stream>>>(Wfc2, Wf2b);
  fused_all<<<B, 512, 0, stream>>>(x, Wb, bb, tabb, Wf2b, bfc2, out);
}

// Round 10
// 221.826 us; speedup vs baseline: 1.1096x; 1.0426x over previous
//
#include <hip/hip_runtime.h>
#include <hip/hip_bf16.h>
#include <math.h>

// Fused QKV(+bias) -> RoPE -> 4-head causal attention -> FC2(+bias) -> SiLU
// B=2048, L=119, D=128, H=4, HD=32. fp32 in/out, bf16 MFMA internally.
// Head split: model channel c = d*4 + h. Head merge: out channel c' = h*32 + d.
//
// Round 9: 32x32x16 MFMA restructure -- softmax row made LANE-LOCAL.
//  - QK^T swapped (A=K, B=Q): C col = query = lane&31 -> lane owns its query's
//    S values; softmax = in-lane VALU + 1 shfl_xor(32) for max + 1 for sum;
//    P normalized in-lane; PV A-frags via 4 independent shfl_xor(32)/mfma.
//    Cross-lane ops/wave: ~150 serial -> ~45 independent.
//  - QKV unswapped (A=W, B=x): C rows = chans -> RoPE pair (d,d+16) = regs
//    (r,r+8) SAME lane -> RoPE fully in-lane; (2d,2d+1) interleaved store
//    (same perm on q and k => QK^T invariant). SCALE folded into q.
//  - RoPE table staged in LDS stride-65 words (conflict-free reads).
//  - FC2+SiLU phase verbatim from R8 (known-good), after barrier.
// Layouts (guide m74/m101): 32x32 C/D: col=lane&31, row=(reg&3)+8*(reg>>2)
// +4*(lane>>5). A: row=lane&31, k=(lane>>5)*8+j. B: col=lane&31, same k.
// LDS: qs/ks [4][128][40] bf16, vT [4][32][128] XOR ^((d&7)<<3), tabL [119][65] u32.

#define L_SEQ 119
#define D_MODEL 128
#define SCALE 0.17677669529663687f  // 1/sqrt(32)
#define NEGINF -1e30f

typedef __bf16 bf16x8 __attribute__((ext_vector_type(8)));
typedef __bf16 bf16x2 __attribute__((ext_vector_type(2)));
typedef float f32x4 __attribute__((ext_vector_type(4)));
typedef float f32x16 __attribute__((ext_vector_type(16)));

__global__ void rope_tab_kernel(unsigned* __restrict__ tabu) {
  int i = blockIdx.x * blockDim.x + threadIdx.x;
  if (i >= L_SEQ * 64) return;
  int l = i >> 6, j = i & 63;
  float inv = 1.0f / powf(10000.0f, (float)(2 * j) / 128.0f);
  float f = (float)l * inv;
  union { bf16x2 v; unsigned u; } cs;
  cs.v[0] = (__bf16)cosf(f);
  cs.v[1] = (__bf16)sinf(f);
  tabu[i] = cs.u;
}

// Wb: A-operand frags for QKV (A=W). flat = ((nt*8 + ks)*64 + lane)*8 + j
//   row chan d = lane&31 (tile nt = h*3+qkv), k = ks*16 + (lane>>5)*8 + j
//   source: Wqkv[(qkv*128 + d*4 + h)*128 + k]
__global__ void wprep_kernel(const float* __restrict__ Wqkv,
                             const float* __restrict__ bqkv,
                             __bf16* __restrict__ Wb, float* __restrict__ bb2) {
  int i = blockIdx.x * 256 + threadIdx.x;  // 0..49151
  int j = i & 7, lane = (i >> 3) & 63, ks = (i >> 9) & 7, nt = i >> 12;
  int d = lane & 31;
  int h = nt / 3, qkv = nt % 3;
  int k = ks * 16 + (lane >> 5) * 8 + j;
  Wb[i] = (__bf16)Wqkv[(qkv * 128 + d * 4 + h) * 128 + k];
  if (i < 384) {
    int nt2 = i >> 5, dd = i & 31;
    bb2[i] = bqkv[(nt2 % 3) * 128 + dd * 4 + (nt2 / 3)];
  }
}

// Wfc2 B-frags (16x16x32 path, unchanged from R8)
__global__ void wprep2_kernel(const float* __restrict__ Wfc2,
                              __bf16* __restrict__ Wf2b) {
  int i = blockIdx.x * 256 + threadIdx.x;  // 0..16383
  int j = i & 7, lane = (i >> 3) & 63, kb = (i >> 9) & 3, nt = i >> 11;
  int n = nt * 16 + (lane & 15);
  int k = kb * 32 + (lane >> 4) * 8 + j;
  Wf2b[i] = (__bf16)Wfc2[n * 128 + k];
}

__global__ __launch_bounds__(512) void fused_all(
    const float* __restrict__ x, const __bf16* __restrict__ Wb,
    const float* __restrict__ bb2, const unsigned* __restrict__ tabu,
    const __bf16* __restrict__ Wf2b, const float* __restrict__ bfc2,
    float* __restrict__ out) {
  __shared__ __align__(16) __bf16 qs[4 * 128 * 40];   // 40,960 B
  __shared__ __align__(16) __bf16 ksm[4 * 128 * 40];  // 40,960 B
  __shared__ __align__(16) __bf16 vT[4 * 32 * 128];   // 32,768 B (XOR-swizzled)
  __shared__ unsigned tabL[L_SEQ * 65];               // 30,940 B

  const int t = threadIdx.x, b = blockIdx.x;
  const int lane = t & 63, wv = t >> 6;
  const int ln31 = lane & 31, hi = lane >> 5;

  // ---- stage RoPE table (stride 65 words -> conflict-free lane-l reads)
  for (int i = t; i < L_SEQ * 64; i += 512)
    tabL[(i >> 6) * 65 + (i & 63)] = tabu[i];
  // ---- zero vT tail cols 119..127
  for (int i = t; i < 4 * 32 * 9; i += 512) {
    int hd = i / 9, cc = L_SEQ + i % 9, d = hd & 31;
    vT[hd * 128 + (cc ^ ((d & 7) << 3))] = (__bf16)0.0f;
  }
  __syncthreads();

  // ======== QKV: wave -> Mtile (wv&3), Ntile-group (wv>>2)*6 .. +5 ========
  const int mt = wv & 3, g2 = wv >> 2;
  const int l_me = mt * 32 + ln31;         // this lane's sequence row (col of C)
  const bool live = (l_me < L_SEQ);
  {
    int xr = live ? l_me : (L_SEQ - 1);
    const float* xrow = x + ((size_t)b * L_SEQ + xr) * 128;
    bf16x8 af[8];
#pragma unroll
    for (int ks = 0; ks < 8; ++ks) {
      float4 lo = *(const float4*)&xrow[ks * 16 + hi * 8];
      float4 hi4 = *(const float4*)&xrow[ks * 16 + hi * 8 + 4];
      bf16x8 v;
      v[0] = (__bf16)lo.x; v[1] = (__bf16)lo.y; v[2] = (__bf16)lo.z; v[3] = (__bf16)lo.w;
      v[4] = (__bf16)hi4.x; v[5] = (__bf16)hi4.y; v[6] = (__bf16)hi4.z; v[7] = (__bf16)hi4.w;
      af[ks] = v;
    }
#pragma unroll
    for (int r = 0; r < 3; ++r) {
      const int nt0 = g2 * 6 + 2 * r, nt1 = nt0 + 1;
      f32x16 a0 = {}, a1 = {};
#pragma unroll
      for (int ks = 0; ks < 8; ++ks) {
        bf16x8 wf0 = *(const bf16x8*)&Wb[(((nt0 * 8 + ks) * 64) + lane) * 8];
        bf16x8 wf1 = *(const bf16x8*)&Wb[(((nt1 * 8 + ks) * 64) + lane) * 8];
        a0 = __builtin_amdgcn_mfma_f32_32x32x16_bf16(wf0, af[ks], a0, 0, 0, 0);
        a1 = __builtin_amdgcn_mfma_f32_32x32x16_bf16(wf1, af[ks], a1, 0, 0, 0);
      }
      // epilogues (runtime wave-uniform qkv type)
#pragma unroll
      for (int e = 0; e < 2; ++e) {
        const int nt = e ? nt1 : nt0;
        const f32x16& A = e ? a1 : a0;
        const int h = nt / 3, qkv = nt % 3;
        if (qkv < 2) {  // q or k: RoPE in-lane on reg pairs (r, r+8)
          __bf16* base = (qkv == 0) ? qs : ksm;
          if (live) {
#pragma unroll
            for (int rg = 0; rg < 8; ++rg) {
              const int c_lo = (rg & 3) + 8 * (rg >> 2);
              int d = c_lo + 4 * hi;  // 0..15
              union { bf16x2 v; unsigned u; } cs;
              cs.u = tabL[l_me * 65 + 4 * d + h];
              float c = (float)cs.v[0], s = (float)cs.v[1];
              float v1 = A[rg] + bb2[nt * 32 + d];
              float v2 = A[rg + 8] + bb2[nt * 32 + d + 16];
              if (qkv == 0) { v1 *= SCALE; v2 *= SCALE; }
              union { bf16x2 v; unsigned u; } pk;
              pk.v[0] = (__bf16)(v1 * c + v2 * s);
              pk.v[1] = (__bf16)(v2 * c - v1 * s);
              *(unsigned*)&base[(h * 128 + l_me) * 40 + 2 * d] = pk.u;
            }
          }
        } else {  // v: write vT[h][d][l] XOR-swizzled
          if (live) {
#pragma unroll
            for (int rg = 0; rg < 16; ++rg) {
              const int d = (rg & 3) + 8 * (rg >> 2) + 4 * hi;  // 0..31
              float val = A[rg] + bb2[nt * 32 + d];
              vT[(h * 32 + d) * 128 + (l_me ^ ((d & 7) << 3))] = (__bf16)val;
            }
          }
        }
      }
    }
  }
  __syncthreads();

  // ======== attention: wave -> head (wv>>1); tasks qt = {wv&1, 3-(wv&1)} ====
  {
    const int h = wv >> 1;
#pragma unroll
    for (int ts = 0; ts < 2; ++ts) {
      const int qt = ts ? (3 - (wv & 1)) : (wv & 1);
      // Q B-frags: col = query = ln31
      bf16x8 qf0 = *(const bf16x8*)&qs[(h * 128 + qt * 32 + ln31) * 40 + hi * 8];
      bf16x8 qf1 = *(const bf16x8*)&qs[(h * 128 + qt * 32 + ln31) * 40 + 16 + hi * 8];
      f32x16 s[4];
#pragma unroll
      for (int kt = 0; kt < 4; ++kt) {
        if (kt <= qt) {
          bf16x8 kf0 = *(const bf16x8*)&ksm[(h * 128 + kt * 32 + ln31) * 40 + hi * 8];
          bf16x8 kf1 = *(const bf16x8*)&ksm[(h * 128 + kt * 32 + ln31) * 40 + 16 + hi * 8];
          f32x16 z = {};
          z = __builtin_amdgcn_mfma_f32_32x32x16_bf16(kf0, qf0, z, 0, 0, 0);
          s[kt] = __builtin_amdgcn_mfma_f32_32x32x16_bf16(kf1, qf1, z, 0, 0, 0);
        }
      }
      // causal mask (diagonal tile only: key crow > query ln31)
      {
#pragma unroll
        for (int rg = 0; rg < 16; ++rg) {
          const int c_lo = (rg & 3) + 8 * (rg >> 2);
#pragma unroll
          for (int kt = 0; kt < 4; ++kt) {
            if (kt == qt) {
              int crow = c_lo + 4 * hi;
              s[kt][rg] = (crow <= ln31) ? s[kt][rg] : NEGINF;
            }
          }
        }
      }
      // softmax: in-lane + 1 shfl_xor(32) each for max and sum
      float mx = NEGINF;
#pragma unroll
      for (int kt = 0; kt < 4; ++kt)
        if (kt <= qt)
#pragma unroll
          for (int rg = 0; rg < 16; ++rg) mx = fmaxf(mx, s[kt][rg]);
      mx = fmaxf(mx, __shfl_xor(mx, 32));
      float sum = 0.0f;
#pragma unroll
      for (int kt = 0; kt < 4; ++kt)
        if (kt <= qt)
#pragma unroll
          for (int rg = 0; rg < 16; ++rg) {
            s[kt][rg] = __expf(s[kt][rg] - mx);
            sum += s[kt][rg];
          }
      sum += __shfl_xor(sum, 32);
      float inv = 1.0f / sum;
      // normalize in-lane, pack P pairs (keys 2p, 2p+1 of each kt-tile half)
      unsigned pk[4][8];
#pragma unroll
      for (int kt = 0; kt < 4; ++kt) {
        if (kt <= qt) {
#pragma unroll
          for (int p = 0; p < 8; ++p) {
            union { bf16x2 v; unsigned u; } w;
            w.v[0] = (__bf16)(s[kt][2 * p] * inv);
            w.v[1] = (__bf16)(s[kt][2 * p + 1] * inv);
            pk[kt][p] = w.u;
          }
        }
      }
      // PV: A = P (row = query = ln31), frags assembled via 4 shfl_xor(32)
      f32x16 o = {};
#pragma unroll
      for (int kt = 0; kt < 4; ++kt) {
        if (kt <= qt) {
#pragma unroll
          for (int m = 0; m < 2; ++m) {
            unsigned f0 = (unsigned)__shfl_xor((int)pk[kt][4 * m + 0], 32);
            unsigned f1 = (unsigned)__shfl_xor((int)pk[kt][4 * m + 1], 32);
            unsigned f2 = (unsigned)__shfl_xor((int)pk[kt][4 * m + 2], 32);
            unsigned f3 = (unsigned)__shfl_xor((int)pk[kt][4 * m + 3], 32);
            union { unsigned w[4]; bf16x8 v; } Aw;
            Aw.w[0] = hi ? f2 : pk[kt][4 * m + 0];
            Aw.w[1] = hi ? f3 : pk[kt][4 * m + 1];
            Aw.w[2] = hi ? pk[kt][4 * m + 2] : f0;
            Aw.w[3] = hi ? pk[kt][4 * m + 3] : f1;
            bf16x8 vf = *(const bf16x8*)&vT[(h * 32 + ln31) * 128 +
                ((kt * 32 + m * 16 + hi * 8) ^ ((ln31 & 7) << 3))];
            o = __builtin_amdgcn_mfma_f32_32x32x16_bf16(Aw.v, vf, o, 0, 0, 0);
          }
        }
      }
      // store O: col = d = ln31, row = query
#pragma unroll
      for (int rg = 0; rg < 16; ++rg) {
        const int c_lo = (rg & 3) + 8 * (rg >> 2);
        int l = qt * 32 + c_lo + 4 * hi;
        if (l < L_SEQ)
          out[((size_t)b * L_SEQ + l) * 128 + h * 32 + ln31] = o[rg];
      }
    }
  }

  // ======== FC2 + bias + SiLU (verbatim R8; 16x16 path) ========
  __syncthreads();
  {
    const int ln15 = lane & 15, kg = lane >> 4;
    int yr = wv * 16 + ln15;
    if (yr > L_SEQ - 1) yr = L_SEQ - 1;
    const float* yrow = out + ((size_t)b * L_SEQ + yr) * 128;
    bf16x8 af2[4];
#pragma unroll
    for (int kb = 0; kb < 4; ++kb) {
      float4 lo = *(const float4*)&yrow[kb * 32 + kg * 8];
      float4 hi4 = *(const float4*)&yrow[kb * 32 + kg * 8 + 4];
      bf16x8 v;
      v[0] = (__bf16)lo.x; v[1] = (__bf16)lo.y; v[2] = (__bf16)lo.z; v[3] = (__bf16)lo.w;
      v[4] = (__bf16)hi4.x; v[5] = (__bf16)hi4.y; v[6] = (__bf16)hi4.z; v[7] = (__bf16)hi4.w;
      af2[kb] = v;
    }
    float bc[8];
#pragma unroll
    for (int nt = 0; nt < 8; ++nt) bc[nt] = bfc2[nt * 16 + ln15];
    f32x4 acc2[8] = {};
#pragma unroll
    for (int nt = 0; nt < 8; ++nt)
#pragma unroll
      for (int kb = 0; kb < 4; ++kb)
        acc2[nt] = __builtin_amdgcn_mfma_f32_16x16x32_bf16(
            af2[kb], *(const bf16x8*)&Wf2b[(((nt * 4 + kb) * 64) + lane) * 8],
            acc2[nt], 0, 0, 0);
#pragma unroll
    for (int nt = 0; nt < 8; ++nt)
#pragma unroll
      for (int r = 0; r < 4; ++r) {
        int row = wv * 16 + kg * 4 + r, c = nt * 16 + ln15;
        if (row < L_SEQ) {
          float vv = acc2[nt][r] + bc[nt];
          out[((size_t)b * L_SEQ + row) * 128 + c] = vv / (1.0f + __expf(-vv));
        }
      }
  }
}

extern "C" void kernel_launch(void* const* d_in, const int* in_sizes, int n_in,
                              void* d_out, int out_size, void* d_ws,
                              size_t ws_size, hipStream_t stream) {
  const float* x = (const float*)d_in[0];
  const float* Wqkv = (const float*)d_in[1];
  const float* bqkv = (const float*)d_in[2];
  const float* Wfc2 = (const float*)d_in[3];
  const float* bfc2 = (const float*)d_in[4];
  float* out = (float*)d_out;

  char* ws = (char*)d_ws;
  unsigned* tabu = (unsigned*)ws;                        // 30,464 B (pad 30,720)
  __bf16* Wb = (__bf16*)(ws + 30720);                    // 98,304 B
  float* bb2 = (float*)(ws + 30720 + 98304);             //  1,536 B
  __bf16* Wf2b = (__bf16*)(ws + 30720 + 98304 + 1536);   // 32,768 B (end 163,328)

  const int B = in_sizes[0] / (L_SEQ * D_MODEL);  // 2048
  rope_tab_kernel<<<(L_SEQ * 64 + 255) / 256, 256, 0, stream>>>(tabu);
  wprep_kernel<<<192, 256, 0, stream>>>(Wqkv, bqkv, Wb, bb2);
  wprep2_kernel<<<64, 256, 0, stream>>>(Wfc2, Wf2b);
  fused_all<<<B, 512, 0, stream>>>(x, Wb, bb2, tabu, Wf2b, bfc2, out);
}